// Round 1
// baseline (863.058 us; speedup 1.0000x reference)
//
#include <hip/hip_runtime.h>

typedef unsigned short ushort_t;
typedef __bf16  bf16x8 __attribute__((ext_vector_type(8)));
typedef float   f32x4  __attribute__((ext_vector_type(4)));
typedef unsigned short us8 __attribute__((ext_vector_type(8)));
typedef _Float16 f16x8 __attribute__((ext_vector_type(8)));
typedef float   fl4   __attribute__((ext_vector_type(4)));

__device__ __forceinline__ ushort_t f2bf(float f) {
    union { float f; unsigned u; } x; x.f = f;
    unsigned r = x.u + 0x7fffu + ((x.u >> 16) & 1u);
    return (ushort_t)(r >> 16);
}

// ---------------- fp32 -> bf16 cast, vectorized ----------------
__global__ __launch_bounds__(256) void cvt_f32_bf16(const float* __restrict__ in,
                                                    ushort_t* __restrict__ out, int n8) {
    int i = blockIdx.x * blockDim.x + threadIdx.x;
    int stride = gridDim.x * blockDim.x;
    for (; i < n8; i += stride) {
        const fl4* p = (const fl4*)(in + (long)i * 8);
        fl4 a = p[0], b = p[1];
        us8 o;
#pragma unroll
        for (int j = 0; j < 4; ++j) { o[j] = f2bf(a[j]); o[4 + j] = f2bf(b[j]); }
        *(us8*)(out + (long)i * 8) = o;
    }
}

// ---------------- 128x128 tile bf16 GEMM, C = A * B^T (m97 structure) ----------------
// A: [M, lda] bf16 row-major; B: [N, ldb] bf16 row-major (i.e. B^T in math terms).
// MODE 0: bf16 out, + bias[col]
// MODE 1: bf16 out, + bias[row]
// MODE 2: fp16 out, * scale
// MODE 3: fp32 out
template <int MODE>
__global__ __launch_bounds__(256) void gemm_bt(const ushort_t* __restrict__ A,
                                               const ushort_t* __restrict__ B,
                                               void* __restrict__ Cout,
                                               const float* __restrict__ bias,
                                               float scale, int K,
                                               int lda, int ldb, int ldc) {
    __shared__ ushort_t As[128 * 32];
    __shared__ ushort_t Bs[128 * 32];

    const int t    = threadIdx.x;
    const int lane = t & 63;
    const int wid  = t >> 6;
    const int wr   = wid >> 1;    // wave row (0..1)
    const int wc   = wid & 1;     // wave col (0..1)
    const int fr   = lane & 15;   // fragment row/col
    const int kq   = lane >> 4;   // k-quarter (0..3)

    const long brow = (long)blockIdx.y * 128;
    const long bcol = (long)blockIdx.x * 128;

    // staging: 2 chunks of 16B per thread per tile; LDS layout linear [128][32]
    const int e0 = t * 8;            // first 8-elem group
    const int e1 = t * 8 + 2048;     // second
    const ushort_t* ga0 = A + (brow + (e0 >> 5)) * lda + (e0 & 31);
    const ushort_t* ga1 = A + (brow + (e1 >> 5)) * lda + (e1 & 31);
    const ushort_t* gb0 = B + (bcol + (e0 >> 5)) * ldb + (e0 & 31);
    const ushort_t* gb1 = B + (bcol + (e1 >> 5)) * ldb + (e1 & 31);
    auto* la0 = (__attribute__((address_space(3))) unsigned int*)&As[e0];
    auto* la1 = (__attribute__((address_space(3))) unsigned int*)&As[e1];
    auto* lb0 = (__attribute__((address_space(3))) unsigned int*)&Bs[e0];
    auto* lb1 = (__attribute__((address_space(3))) unsigned int*)&Bs[e1];

    f32x4 acc[4][4] = {};

    const int nk = K >> 5;
    for (int kt = 0; kt < nk; ++kt) {
        __builtin_amdgcn_global_load_lds((const __attribute__((address_space(1))) unsigned int*)ga0, la0, 16, 0, 0);
        __builtin_amdgcn_global_load_lds((const __attribute__((address_space(1))) unsigned int*)ga1, la1, 16, 0, 0);
        __builtin_amdgcn_global_load_lds((const __attribute__((address_space(1))) unsigned int*)gb0, lb0, 16, 0, 0);
        __builtin_amdgcn_global_load_lds((const __attribute__((address_space(1))) unsigned int*)gb1, lb1, 16, 0, 0);
        ga0 += 32; ga1 += 32; gb0 += 32; gb1 += 32;
        __syncthreads();   // drains vmcnt -> LDS visible

        bf16x8 af[4], bfr[4];
#pragma unroll
        for (int m = 0; m < 4; ++m)
            af[m] = *(const bf16x8*)&As[(wr * 64 + m * 16 + fr) * 32 + kq * 8];
#pragma unroll
        for (int n = 0; n < 4; ++n)
            bfr[n] = *(const bf16x8*)&Bs[(wc * 64 + n * 16 + fr) * 32 + kq * 8];
#pragma unroll
        for (int m = 0; m < 4; ++m)
#pragma unroll
            for (int n = 0; n < 4; ++n)
                acc[m][n] = __builtin_amdgcn_mfma_f32_16x16x32_bf16(af[m], bfr[n], acc[m][n], 0, 0, 0);
        __syncthreads();   // protect LDS from next stage
    }

    // epilogue: C/D layout col=lane&15, row=(lane>>4)*4+j
#pragma unroll
    for (int m = 0; m < 4; ++m) {
#pragma unroll
        for (int n = 0; n < 4; ++n) {
#pragma unroll
            for (int j = 0; j < 4; ++j) {
                long r = brow + wr * 64 + m * 16 + kq * 4 + j;
                long c = bcol + wc * 64 + n * 16 + fr;
                float v = acc[m][n][j];
                if (MODE == 0) { v += bias[c]; ((ushort_t*)Cout)[r * ldc + c] = f2bf(v); }
                else if (MODE == 1) { v += bias[r]; ((ushort_t*)Cout)[r * ldc + c] = f2bf(v); }
                else if (MODE == 2) { ((_Float16*)Cout)[r * ldc + c] = (_Float16)(v * scale); }
                else { ((float*)Cout)[r * ldc + c] = v; }
            }
        }
    }
}

// ---------------- row softmax: fp16 in -> bf16 out, in place, L=4096 ----------------
__global__ __launch_bounds__(256) void softmax_row(ushort_t* __restrict__ S, int L) {
    const long row = blockIdx.x;
    ushort_t* rp = S + row * L;
    const int t = threadIdx.x;
    const int lane = t & 63, wid = t >> 6;

    f16x8 h0 = *(const f16x8*)(rp + t * 16);
    f16x8 h1 = *(const f16x8*)(rp + t * 16 + 8);
    float x[16];
#pragma unroll
    for (int j = 0; j < 8; ++j) { x[j] = (float)h0[j]; x[8 + j] = (float)h1[j]; }

    float m = -1e30f;
#pragma unroll
    for (int j = 0; j < 16; ++j) m = fmaxf(m, x[j]);
#pragma unroll
    for (int o = 32; o; o >>= 1) m = fmaxf(m, __shfl_xor(m, o));

    __shared__ float redmax[4], redsum[4];
    if (lane == 0) redmax[wid] = m;
    __syncthreads();
    m = fmaxf(fmaxf(redmax[0], redmax[1]), fmaxf(redmax[2], redmax[3]));

    float e[16], s = 0.f;
#pragma unroll
    for (int j = 0; j < 16; ++j) { e[j] = __expf(x[j] - m); s += e[j]; }
#pragma unroll
    for (int o = 32; o; o >>= 1) s += __shfl_xor(s, o);
    if (lane == 0) redsum[wid] = s;
    __syncthreads();
    s = redsum[0] + redsum[1] + redsum[2] + redsum[3];
    float inv = 1.f / s;

    us8 o0, o1;
#pragma unroll
    for (int j = 0; j < 8; ++j) { o0[j] = f2bf(e[j] * inv); o1[j] = f2bf(e[8 + j] * inv); }
    *(us8*)(rp + t * 16) = o0;
    *(us8*)(rp + t * 16 + 8) = o1;
}

extern "C" void kernel_launch(void* const* d_in, const int* in_sizes, int n_in,
                              void* d_out, int out_size, void* d_ws, size_t ws_size,
                              hipStream_t stream) {
    (void)in_sizes; (void)n_in; (void)out_size; (void)ws_size;
    const float* q  = (const float*)d_in[0];
    const float* k  = (const float*)d_in[1];
    const float* v  = (const float*)d_in[2];
    const float* Wq = (const float*)d_in[3];
    const float* bq = (const float*)d_in[4];
    const float* Wk = (const float*)d_in[5];
    const float* bk = (const float*)d_in[6];
    const float* Wv = (const float*)d_in[7];
    const float* bv = (const float*)d_in[8];
    float* out = (float*)d_out;

    constexpr long MB = 1l << 20;
    char* ws = (char*)d_ws;
    ushort_t* pq  = (ushort_t*)(ws + 0 * MB);     // 32 MB  [16384,1024] bf16
    ushort_t* pk  = (ushort_t*)(ws + 32 * MB);    // 32 MB
    ushort_t* pvT = (ushort_t*)(ws + 64 * MB);    // 32 MB  [1024,16384] bf16 (pv transposed)
    ushort_t* Wqb = (ushort_t*)(ws + 96 * MB);    // 2 MB
    ushort_t* Wkb = (ushort_t*)(ws + 98 * MB);    // 2 MB
    ushort_t* Wvb = (ushort_t*)(ws + 100 * MB);   // 2 MB
    ushort_t* qb  = (ushort_t*)(ws + 104 * MB);   // 32 MB (dead after pq GEMM)
    ushort_t* kb  = (ushort_t*)(ws + 136 * MB);   // 32 MB
    ushort_t* vb  = (ushort_t*)(ws + 168 * MB);   // 32 MB  -> ws end = 200 MB
    ushort_t* S   = (ushort_t*)(ws + 104 * MB);   // 32 MB per batch, aliases qb (dead)

    const int L = 4096, E = 1024, NB = 4;
    const int n8_x = (NB * L * E) / 8;   // 2097152
    const int n8_w = (E * E) / 8;        // 131072

    cvt_f32_bf16<<<2048, 256, 0, stream>>>(q, qb, n8_x);
    cvt_f32_bf16<<<2048, 256, 0, stream>>>(k, kb, n8_x);
    cvt_f32_bf16<<<2048, 256, 0, stream>>>(v, vb, n8_x);
    cvt_f32_bf16<<<512, 256, 0, stream>>>(Wq, Wqb, n8_w);
    cvt_f32_bf16<<<512, 256, 0, stream>>>(Wk, Wkb, n8_w);
    cvt_f32_bf16<<<512, 256, 0, stream>>>(Wv, Wvb, n8_w);

    // projections: pq = q@Wq^T + bq   (M=16384, N=1024, K=1024)
    dim3 gproj(E / 128, (NB * L) / 128);   // (8, 128)
    gemm_bt<0><<<gproj, 256, 0, stream>>>(qb, Wqb, pq, bq, 1.f, E, E, E, E);
    gemm_bt<0><<<gproj, 256, 0, stream>>>(kb, Wkb, pk, bk, 1.f, E, E, E, E);
    // pvT = Wv @ v^T + bv[row]   (M=1024, N=16384, K=1024), C layout [e, n*L+m]
    dim3 gpv((NB * L) / 128, E / 128);     // (128, 8)
    gemm_bt<1><<<gpv, 256, 0, stream>>>(Wvb, vb, pvT, bv, 1.f, E, E, E, NB * L);

    const float scale = 0.03125f;  // 1/sqrt(1024)
    for (int n = 0; n < NB; ++n) {
        const ushort_t* pqn = pq + (long)n * L * E;
        const ushort_t* pkn = pk + (long)n * L * E;
        // S = pq @ pk^T * scale  -> fp16  (M=N=4096, K=1024)
        gemm_bt<2><<<dim3(L / 128, L / 128), 256, 0, stream>>>(pqn, pkn, (void*)S, nullptr, scale, E, E, E, L);
        // softmax rows, in place fp16 -> bf16
        softmax_row<<<L, 256, 0, stream>>>(S, L);
        // out = attn @ pv = attn @ pvT^T   (M=4096, N=1024, K=4096)
        gemm_bt<3><<<dim3(E / 128, L / 128), 256, 0, stream>>>(S, pvT + (long)n * L,
                                                               out + (long)n * L * E, nullptr, 1.f,
                                                               L, L, NB * L, E);
    }
}

// Round 2
// 539.852 us; speedup vs baseline: 1.5987x; 1.5987x over previous
//
#include <hip/hip_runtime.h>

typedef unsigned short u16;
typedef __bf16  bf16x8 __attribute__((ext_vector_type(8)));
typedef float   f32x4  __attribute__((ext_vector_type(4)));
typedef unsigned short us8 __attribute__((ext_vector_type(8)));
typedef _Float16 f16x8 __attribute__((ext_vector_type(8)));
typedef float   fl4   __attribute__((ext_vector_type(4)));

#define AS1 __attribute__((address_space(1)))
#define AS3 __attribute__((address_space(3)))

__device__ __forceinline__ u16 f2bf(float f) {
    union { float f; unsigned u; } x; x.f = f;
    unsigned r = x.u + 0x7fffu + ((x.u >> 16) & 1u);
    return (u16)(r >> 16);
}

// ---------------- fp32 -> bf16 cast, vectorized ----------------
__global__ __launch_bounds__(256) void cvt_f32_bf16(const float* __restrict__ in,
                                                    u16* __restrict__ out, int n8) {
    int i = blockIdx.x * blockDim.x + threadIdx.x;
    int stride = gridDim.x * blockDim.x;
    for (; i < n8; i += stride) {
        const fl4* p = (const fl4*)(in + (long)i * 8);
        fl4 a = p[0], b = p[1];
        us8 o;
#pragma unroll
        for (int j = 0; j < 4; ++j) { o[j] = f2bf(a[j]); o[4 + j] = f2bf(b[j]); }
        *(us8*)(out + (long)i * 8) = o;
    }
}

// ---------------- 256x128 tile bf16 GEMM, C = A * B^T ----------------
// 3-buffer LDS pipeline, BK=64, counted vmcnt(6), swizzled LDS, 8 waves (4Mx2N).
// A: [M, lda] bf16 row-major; B: [N, ldb] bf16 row-major.
// MODE 0: bf16 out + bias[col]; MODE 1: bf16 out + bias[row];
// MODE 2: fp16 out * scale;     MODE 3: fp32 out.
template <int MODE>
__global__ __launch_bounds__(512, 1) void gemm256(const u16* __restrict__ A,
                                                  const u16* __restrict__ B,
                                                  void* __restrict__ Cout,
                                                  const float* __restrict__ bias,
                                                  float scale, int K,
                                                  int lda, int ldb, int ldc,
                                                  long sAz, long sBz, long sCz) {
    // per buffer: A 256x64 bf16 = 32768 B, B 128x64 bf16 = 16384 B -> 49152 B; x3 = 144 KiB
    __shared__ alignas(16) char lds8[3 * 49152];

    const int t    = threadIdx.x;
    const int lane = t & 63;
    const int wid  = t >> 6;      // 0..7
    const int wr   = wid >> 1;    // 0..3  (64-row slice of 256)
    const int wc   = wid & 1;     // 0..1  (64-col slice of 128)
    const int fr   = lane & 15;
    const int kq   = lane >> 4;

    // XCD-bijective block swizzle (nwg % 8 == 0 for all our launches)
    const int gx  = gridDim.x;
    const int nwg = gx * gridDim.y;
    const int wg  = blockIdx.y * gx + blockIdx.x;
    const int swz = (wg & 7) * (nwg >> 3) + (wg >> 3);
    const long brow = (long)(swz / gx) * 256;
    const long bcol = (long)(swz % gx) * 128;

    const u16* Az = A + sAz * blockIdx.z;
    const u16* Bz = B + sBz * blockIdx.z;

    // staging: physical LDS byte p = r*8192 + t*16 holds logical chunk (t&7)^(row&7)
    const int trow = t >> 3;
    const int tc8  = ((t & 7) ^ (trow & 7)) * 8;   // element offset of logical chunk
    long offA[4], offB[2];
#pragma unroll
    for (int r = 0; r < 4; ++r) offA[r] = (brow + r * 64 + trow) * (long)lda + tc8;
#pragma unroll
    for (int r = 0; r < 2; ++r) offB[r] = (bcol + r * 64 + trow) * (long)ldb + tc8;

    // lane read offsets (swizzled): byte = row*128 + ((ksub*4+kq)^(row&7))*16
    int aRow[4], bRow[4], aCh[2];
#pragma unroll
    for (int m = 0; m < 4; ++m) aRow[m] = (wr * 64 + m * 16 + fr) * 128;
#pragma unroll
    for (int n = 0; n < 4; ++n) bRow[n] = 32768 + (wc * 64 + n * 16 + fr) * 128;
#pragma unroll
    for (int ks = 0; ks < 2; ++ks) aCh[ks] = (((ks << 2) | kq) ^ (fr & 7)) * 16;

    const int NT = K >> 6;
    f32x4 acc[4][4] = {};

    // ---- prologue: stage tiles 0 and 1, drain tile 0 only (leave 6 in flight)
    {
        char* bb0 = lds8;
        char* bb1 = lds8 + 49152;
#pragma unroll
        for (int r = 0; r < 4; ++r)
            __builtin_amdgcn_global_load_lds((const AS1 unsigned*)(Az + offA[r]),
                                             (AS3 unsigned*)(bb0 + r * 8192 + t * 16), 16, 0, 0);
#pragma unroll
        for (int r = 0; r < 2; ++r)
            __builtin_amdgcn_global_load_lds((const AS1 unsigned*)(Bz + offB[r]),
                                             (AS3 unsigned*)(bb0 + 32768 + r * 8192 + t * 16), 16, 0, 0);
#pragma unroll
        for (int r = 0; r < 4; ++r)
            __builtin_amdgcn_global_load_lds((const AS1 unsigned*)(Az + offA[r] + 64),
                                             (AS3 unsigned*)(bb1 + r * 8192 + t * 16), 16, 0, 0);
#pragma unroll
        for (int r = 0; r < 2; ++r)
            __builtin_amdgcn_global_load_lds((const AS1 unsigned*)(Bz + offB[r] + 64),
                                             (AS3 unsigned*)(bb1 + 32768 + r * 8192 + t * 16), 16, 0, 0);
    }
    asm volatile("s_waitcnt vmcnt(6)" ::: "memory");
    __builtin_amdgcn_s_barrier();

    int cur = 0;
    for (int T = 0; T < NT; ++T) {
        char* bb = lds8 + cur * 49152;
        int nb = cur + 2; if (nb >= 3) nb -= 3;
        char* bbn = lds8 + nb * 49152;
        const bool stage = (T + 2) < NT;
        const long kcol = (long)(T + 2) << 6;

        // ---- phase 0 (ksub 0): 8 ds_read + 3 stage-loads + 16 MFMA
        {
            bf16x8 af[4], bfv[4];
#pragma unroll
            for (int m = 0; m < 4; ++m) af[m] = *(const bf16x8*)(bb + aRow[m] + aCh[0]);
#pragma unroll
            for (int n = 0; n < 4; ++n) bfv[n] = *(const bf16x8*)(bb + bRow[n] + aCh[0]);
            if (stage) {
#pragma unroll
                for (int r = 0; r < 3; ++r)
                    __builtin_amdgcn_global_load_lds((const AS1 unsigned*)(Az + offA[r] + kcol),
                                                     (AS3 unsigned*)(bbn + r * 8192 + t * 16), 16, 0, 0);
            }
            __builtin_amdgcn_s_barrier();
            __builtin_amdgcn_sched_barrier(0);
            __builtin_amdgcn_s_setprio(1);
#pragma unroll
            for (int m = 0; m < 4; ++m)
#pragma unroll
                for (int n = 0; n < 4; ++n)
                    acc[m][n] = __builtin_amdgcn_mfma_f32_16x16x32_bf16(af[m], bfv[n], acc[m][n], 0, 0, 0);
            __builtin_amdgcn_s_setprio(0);
            __builtin_amdgcn_sched_barrier(0);
            __builtin_amdgcn_s_barrier();
        }
        // ---- phase 1 (ksub 1): 8 ds_read + 3 stage-loads + 16 MFMA + boundary wait
        {
            bf16x8 af[4], bfv[4];
#pragma unroll
            for (int m = 0; m < 4; ++m) af[m] = *(const bf16x8*)(bb + aRow[m] + aCh[1]);
#pragma unroll
            for (int n = 0; n < 4; ++n) bfv[n] = *(const bf16x8*)(bb + bRow[n] + aCh[1]);
            if (stage) {
                __builtin_amdgcn_global_load_lds((const AS1 unsigned*)(Az + offA[3] + kcol),
                                                 (AS3 unsigned*)(bbn + 3 * 8192 + t * 16), 16, 0, 0);
#pragma unroll
                for (int r = 0; r < 2; ++r)
                    __builtin_amdgcn_global_load_lds((const AS1 unsigned*)(Bz + offB[r] + kcol),
                                                     (AS3 unsigned*)(bbn + 32768 + r * 8192 + t * 16), 16, 0, 0);
            }
            __builtin_amdgcn_s_barrier();
            __builtin_amdgcn_sched_barrier(0);
            __builtin_amdgcn_s_setprio(1);
#pragma unroll
            for (int m = 0; m < 4; ++m)
#pragma unroll
                for (int n = 0; n < 4; ++n)
                    acc[m][n] = __builtin_amdgcn_mfma_f32_16x16x32_bf16(af[m], bfv[n], acc[m][n], 0, 0, 0);
            __builtin_amdgcn_s_setprio(0);
            __builtin_amdgcn_sched_barrier(0);
            if (T + 1 < NT) {
                // drain tile T+1's 6 loads; leave tile T+2's 6 in flight (buf nobody reads)
                if (stage) asm volatile("s_waitcnt vmcnt(6)" ::: "memory");
                else       asm volatile("s_waitcnt vmcnt(0)" ::: "memory");
                __builtin_amdgcn_s_barrier();
            }
        }
        cur = cur + 1; if (cur == 3) cur = 0;
    }

    // ---- epilogue: C/D layout col=lane&15, row=(lane>>4)*4+j
    const long crow = brow + wr * 64;
    const long ccol = bcol + wc * 64;
    const long cz = sCz * blockIdx.z;
#pragma unroll
    for (int m = 0; m < 4; ++m) {
#pragma unroll
        for (int n = 0; n < 4; ++n) {
#pragma unroll
            for (int j = 0; j < 4; ++j) {
                long r = crow + m * 16 + kq * 4 + j;
                long c = ccol + n * 16 + fr;
                float vv = acc[m][n][j];
                if (MODE == 0)      { vv += bias[c]; ((u16*)Cout)[cz + r * ldc + c] = f2bf(vv); }
                else if (MODE == 1) { vv += bias[r]; ((u16*)Cout)[cz + r * ldc + c] = f2bf(vv); }
                else if (MODE == 2) { ((_Float16*)Cout)[cz + r * ldc + c] = (_Float16)(vv * scale); }
                else                { ((float*)Cout)[cz + r * ldc + c] = vv; }
            }
        }
    }
}

// ---------------- row softmax: fp16 in -> bf16 out, in place, L=4096 ----------------
__global__ __launch_bounds__(256) void softmax_row(u16* __restrict__ S, int L) {
    const long row = blockIdx.x;
    u16* rp = S + row * L;
    const int t = threadIdx.x;
    const int lane = t & 63, wid = t >> 6;

    f16x8 h0 = *(const f16x8*)(rp + t * 16);
    f16x8 h1 = *(const f16x8*)(rp + t * 16 + 8);
    float x[16];
#pragma unroll
    for (int j = 0; j < 8; ++j) { x[j] = (float)h0[j]; x[8 + j] = (float)h1[j]; }

    float m = -1e30f;
#pragma unroll
    for (int j = 0; j < 16; ++j) m = fmaxf(m, x[j]);
#pragma unroll
    for (int o = 32; o; o >>= 1) m = fmaxf(m, __shfl_xor(m, o));

    __shared__ float redmax[4], redsum[4];
    if (lane == 0) redmax[wid] = m;
    __syncthreads();
    m = fmaxf(fmaxf(redmax[0], redmax[1]), fmaxf(redmax[2], redmax[3]));

    float e[16], s = 0.f;
#pragma unroll
    for (int j = 0; j < 16; ++j) { e[j] = __expf(x[j] - m); s += e[j]; }
#pragma unroll
    for (int o = 32; o; o >>= 1) s += __shfl_xor(s, o);
    if (lane == 0) redsum[wid] = s;
    __syncthreads();
    s = redsum[0] + redsum[1] + redsum[2] + redsum[3];
    float inv = 1.f / s;

    us8 o0, o1;
#pragma unroll
    for (int j = 0; j < 8; ++j) { o0[j] = f2bf(e[j] * inv); o1[j] = f2bf(e[8 + j] * inv); }
    *(us8*)(rp + t * 16) = o0;
    *(us8*)(rp + t * 16 + 8) = o1;
}

extern "C" void kernel_launch(void* const* d_in, const int* in_sizes, int n_in,
                              void* d_out, int out_size, void* d_ws, size_t ws_size,
                              hipStream_t stream) {
    (void)in_sizes; (void)n_in; (void)out_size; (void)ws_size;
    const float* q  = (const float*)d_in[0];
    const float* k  = (const float*)d_in[1];
    const float* v  = (const float*)d_in[2];
    const float* Wq = (const float*)d_in[3];
    const float* bq = (const float*)d_in[4];
    const float* Wk = (const float*)d_in[5];
    const float* bk = (const float*)d_in[6];
    const float* Wv = (const float*)d_in[7];
    const float* bv = (const float*)d_in[8];
    float* out = (float*)d_out;

    constexpr long MB = 1l << 20;
    char* ws = (char*)d_ws;
    u16* pq  = (u16*)(ws + 0 * MB);     // 32 MB  [16384,1024] bf16
    u16* pk  = (u16*)(ws + 32 * MB);    // 32 MB
    u16* pvT = (u16*)(ws + 64 * MB);    // 32 MB  [1024,16384] bf16 (pv transposed)
    u16* Wqb = (u16*)(ws + 96 * MB);    // 2 MB
    u16* Wkb = (u16*)(ws + 98 * MB);    // 2 MB
    u16* Wvb = (u16*)(ws + 100 * MB);   // 2 MB
    u16* qb  = (u16*)(ws + 104 * MB);   // 32 MB (dead after pq GEMM)
    u16* kb  = (u16*)(ws + 136 * MB);   // 32 MB (dead after pk GEMM)
    u16* vb  = (u16*)(ws + 168 * MB);   // 32 MB -> ws end = 200 MB
    u16* S2  = (u16*)(ws + 104 * MB);   // 64 MB (2 batches), aliases qb+kb (dead)

    const int L = 4096, E = 1024, NB = 4;
    const int n8_x = (NB * L * E) / 8;
    const int n8_w = (E * E) / 8;

    cvt_f32_bf16<<<2048, 256, 0, stream>>>(q, qb, n8_x);
    cvt_f32_bf16<<<2048, 256, 0, stream>>>(k, kb, n8_x);
    cvt_f32_bf16<<<2048, 256, 0, stream>>>(v, vb, n8_x);
    cvt_f32_bf16<<<512, 256, 0, stream>>>(Wq, Wqb, n8_w);
    cvt_f32_bf16<<<512, 256, 0, stream>>>(Wk, Wkb, n8_w);
    cvt_f32_bf16<<<512, 256, 0, stream>>>(Wv, Wvb, n8_w);

    // projections: pq = q@Wq^T + bq   (M=16384 -> gy=64, N=1024 -> gx=8)
    dim3 gproj(8, 64, 1);
    gemm256<0><<<gproj, 512, 0, stream>>>(qb, Wqb, pq, bq, 1.f, E, E, E, E, 0, 0, 0);
    gemm256<0><<<gproj, 512, 0, stream>>>(kb, Wkb, pk, bk, 1.f, E, E, E, E, 0, 0, 0);
    // pvT = Wv @ v^T + bv[row]   (M=1024 -> gy=4, N=16384 -> gx=128)
    dim3 gpv(128, 4, 1);
    gemm256<1><<<gpv, 512, 0, stream>>>(Wvb, vb, pvT, bv, 1.f, E, E, E, NB * L, 0, 0, 0);

    const float scale = 0.03125f;  // 1/sqrt(1024)
    for (int p = 0; p < 2; ++p) {
        const long zb = p * 2;
        // S = pq @ pk^T * scale -> fp16   (M=N=4096 -> gy=16, gx=32; z=2 batches)
        dim3 gs(32, 16, 2);
        gemm256<2><<<gs, 512, 0, stream>>>(pq + zb * L * E, pk + zb * L * E, (void*)S2,
                                           nullptr, scale, E, E, E, L,
                                           (long)L * E, (long)L * E, (long)L * L);
        // softmax over 2*L rows, in place fp16 -> bf16
        softmax_row<<<2 * L, 256, 0, stream>>>(S2, L);
        // out = attn @ pvT^T   (M=4096 -> gy=16, N=1024 -> gx=8; z=2)
        dim3 gp(8, 16, 2);
        gemm256<3><<<gp, 512, 0, stream>>>(S2, pvT + zb * L, out + zb * L * E,
                                           nullptr, 1.f, L, L, NB * L, E,
                                           (long)L * L, (long)L, (long)L * E);
    }
}

// Round 4
// 519.846 us; speedup vs baseline: 1.6602x; 1.0385x over previous
//
#include <hip/hip_runtime.h>

typedef unsigned short u16;
typedef __bf16  bf16x8 __attribute__((ext_vector_type(8)));
typedef float   f32x4  __attribute__((ext_vector_type(4)));
typedef unsigned short us8 __attribute__((ext_vector_type(8)));
typedef _Float16 f16x8 __attribute__((ext_vector_type(8)));
typedef float   fl4   __attribute__((ext_vector_type(4)));

#define AS1 __attribute__((address_space(1)))
#define AS3 __attribute__((address_space(3)))

__device__ __forceinline__ u16 f2bf(float f) {
    union { float f; unsigned u; } x; x.f = f;
    unsigned r = x.u + 0x7fffu + ((x.u >> 16) & 1u);
    return (u16)(r >> 16);
}

// ---------------- fp32 -> bf16 cast, vectorized ----------------
__global__ __launch_bounds__(256) void cvt_f32_bf16(const float* __restrict__ in,
                                                    u16* __restrict__ out, int n8) {
    int i = blockIdx.x * blockDim.x + threadIdx.x;
    int stride = gridDim.x * blockDim.x;
    for (; i < n8; i += stride) {
        const fl4* p = (const fl4*)(in + (long)i * 8);
        fl4 a = p[0], b = p[1];
        us8 o;
#pragma unroll
        for (int j = 0; j < 4; ++j) { o[j] = f2bf(a[j]); o[4 + j] = f2bf(b[j]); }
        *(us8*)(out + (long)i * 8) = o;
    }
}

// ---------------- 256x128 tile bf16 GEMM, C = A * B^T ----------------
// PROVABLY RACE-FREE schedule (drain-all at every tile boundary):
//   per tile: issue stage(T+1) FIRST (full-tile latency cover), 16 ds_read,
//   32 MFMA, __syncthreads() (vmcnt0+lgkmcnt0+barrier). 2-buffer LDS.
// No in-flight LDS writes ever cross a barrier -> correctness structural.
// Swizzled LDS (bank-conflict-free), XCD-bijective block swizzle, setprio.
// MODE 0: bf16 out + bias[col]; MODE 1: bf16 out + bias[row];
// MODE 2: fp16 out * scale;     MODE 3: fp32 out.
template <int MODE>
__global__ __launch_bounds__(512, 1) void gemm256(const u16* __restrict__ A,
                                                  const u16* __restrict__ B,
                                                  void* __restrict__ Cout,
                                                  const float* __restrict__ bias,
                                                  float scale, int K,
                                                  int lda, int ldb, int ldc,
                                                  long sAz, long sBz, long sCz) {
    // per buffer: A 256x64 bf16 = 32768 B, B 128x64 bf16 = 16384 B -> 49152 B; x2 = 96 KiB
    __shared__ alignas(16) char lds8[2 * 49152];

    const int t    = threadIdx.x;
    const int lane = t & 63;
    const int wid  = t >> 6;      // 0..7
    const int wr   = wid >> 1;    // 0..3  (64-row slice of 256)
    const int wc   = wid & 1;     // 0..1  (64-col slice of 128)
    const int fr   = lane & 15;
    const int kq   = lane >> 4;

    // XCD-bijective block swizzle (nwg % 8 == 0 for all our launches)
    const int gx  = gridDim.x;
    const int nwg = gx * gridDim.y;
    const int wg  = blockIdx.y * gx + blockIdx.x;
    const int swz = (wg & 7) * (nwg >> 3) + (wg >> 3);
    const long brow = (long)(swz / gx) * 256;
    const long bcol = (long)(swz % gx) * 128;

    const u16* Az = A + sAz * blockIdx.z;
    const u16* Bz = B + sBz * blockIdx.z;

    // staging: physical LDS byte p = r*8192 + t*16 holds logical chunk (t&7)^(row&7)
    const int trow = t >> 3;
    const int tc8  = ((t & 7) ^ (trow & 7)) * 8;   // element offset of logical chunk
    long offA[4], offB[2];
#pragma unroll
    for (int r = 0; r < 4; ++r) offA[r] = (brow + r * 64 + trow) * (long)lda + tc8;
#pragma unroll
    for (int r = 0; r < 2; ++r) offB[r] = (bcol + r * 64 + trow) * (long)ldb + tc8;

    // lane read offsets (swizzled): byte = row*128 + ((ksub*4+kq)^(row&7))*16
    int aRow[4], bRow[4], aCh[2];
#pragma unroll
    for (int m = 0; m < 4; ++m) aRow[m] = (wr * 64 + m * 16 + fr) * 128;
#pragma unroll
    for (int n = 0; n < 4; ++n) bRow[n] = 32768 + (wc * 64 + n * 16 + fr) * 128;
#pragma unroll
    for (int ks = 0; ks < 2; ++ks) aCh[ks] = (((ks << 2) | kq) ^ (fr & 7)) * 16;

    const int NT = K >> 6;
    f32x4 acc[4][4] = {};

    // ---- prologue: stage tile 0 into buffer 0, full drain
    {
        char* bb0 = lds8;
#pragma unroll
        for (int r = 0; r < 4; ++r)
            __builtin_amdgcn_global_load_lds((const AS1 unsigned*)(Az + offA[r]),
                                             (AS3 unsigned*)(bb0 + r * 8192 + t * 16), 16, 0, 0);
#pragma unroll
        for (int r = 0; r < 2; ++r)
            __builtin_amdgcn_global_load_lds((const AS1 unsigned*)(Bz + offB[r]),
                                             (AS3 unsigned*)(bb0 + 32768 + r * 8192 + t * 16), 16, 0, 0);
    }
    __syncthreads();

    int cur = 0;
    for (int T = 0; T < NT; ++T) {
        char* bb  = lds8 + cur * 49152;
        char* bbn = lds8 + (cur ^ 1) * 49152;

        // ---- issue next-tile stage FIRST: latency covered by this tile's work.
        // Writes go to bbn, which no wave reads this tile (read buffer is bb;
        // previous tile's reads of bbn completed before last __syncthreads).
        if (T + 1 < NT) {
            const long kcol = (long)(T + 1) << 6;
#pragma unroll
            for (int r = 0; r < 4; ++r)
                __builtin_amdgcn_global_load_lds((const AS1 unsigned*)(Az + offA[r] + kcol),
                                                 (AS3 unsigned*)(bbn + r * 8192 + t * 16), 16, 0, 0);
#pragma unroll
            for (int r = 0; r < 2; ++r)
                __builtin_amdgcn_global_load_lds((const AS1 unsigned*)(Bz + offB[r] + kcol),
                                                 (AS3 unsigned*)(bbn + 32768 + r * 8192 + t * 16), 16, 0, 0);
        }

        // ---- read all fragments for this tile (16 x ds_read_b128, conflict-free)
        bf16x8 af[2][4], bfv[2][4];
#pragma unroll
        for (int ks = 0; ks < 2; ++ks)
#pragma unroll
            for (int m = 0; m < 4; ++m)
                af[ks][m] = *(const bf16x8*)(bb + aRow[m] + aCh[ks]);
#pragma unroll
        for (int ks = 0; ks < 2; ++ks)
#pragma unroll
            for (int n = 0; n < 4; ++n)
                bfv[ks][n] = *(const bf16x8*)(bb + bRow[n] + aCh[ks]);

        asm volatile("s_waitcnt lgkmcnt(0)" ::: "memory");
        __builtin_amdgcn_sched_barrier(0);
        __builtin_amdgcn_s_setprio(1);
#pragma unroll
        for (int ks = 0; ks < 2; ++ks)
#pragma unroll
            for (int m = 0; m < 4; ++m)
#pragma unroll
                for (int n = 0; n < 4; ++n)
                    acc[m][n] = __builtin_amdgcn_mfma_f32_16x16x32_bf16(af[ks][m], bfv[ks][n], acc[m][n], 0, 0, 0);
        __builtin_amdgcn_s_setprio(0);
        __builtin_amdgcn_sched_barrier(0);

        // full drain: stage loads landed, all LDS reads done -> next tile safe
        __syncthreads();
        cur ^= 1;
    }

    // ---- epilogue: C/D layout col=lane&15, row=(lane>>4)*4+j
    const long crow = brow + wr * 64;
    const long ccol = bcol + wc * 64;
    const long cz = sCz * blockIdx.z;
#pragma unroll
    for (int m = 0; m < 4; ++m) {
#pragma unroll
        for (int n = 0; n < 4; ++n) {
#pragma unroll
            for (int j = 0; j < 4; ++j) {
                long r = crow + m * 16 + kq * 4 + j;
                long c = ccol + n * 16 + fr;
                float vv = acc[m][n][j];
                if (MODE == 0)      { vv += bias[c]; ((u16*)Cout)[cz + r * ldc + c] = f2bf(vv); }
                else if (MODE == 1) { vv += bias[r]; ((u16*)Cout)[cz + r * ldc + c] = f2bf(vv); }
                else if (MODE == 2) { ((_Float16*)Cout)[cz + r * ldc + c] = (_Float16)(vv * scale); }
                else                { ((float*)Cout)[cz + r * ldc + c] = vv; }
            }
        }
    }
}

// ---------------- row softmax: fp16 in -> bf16 out, in place, L=4096 ----------------
__global__ __launch_bounds__(256) void softmax_row(u16* __restrict__ S, int L) {
    const long row = blockIdx.x;
    u16* rp = S + row * L;
    const int t = threadIdx.x;
    const int lane = t & 63, wid = t >> 6;

    f16x8 h0 = *(const f16x8*)(rp + t * 16);
    f16x8 h1 = *(const f16x8*)(rp + t * 16 + 8);
    float x[16];
#pragma unroll
    for (int j = 0; j < 8; ++j) { x[j] = (float)h0[j]; x[8 + j] = (float)h1[j]; }

    float m = -1e30f;
#pragma unroll
    for (int j = 0; j < 16; ++j) m = fmaxf(m, x[j]);
#pragma unroll
    for (int o = 32; o; o >>= 1) m = fmaxf(m, __shfl_xor(m, o));

    __shared__ float redmax[4], redsum[4];
    if (lane == 0) redmax[wid] = m;
    __syncthreads();
    m = fmaxf(fmaxf(redmax[0], redmax[1]), fmaxf(redmax[2], redmax[3]));

    float e[16], s = 0.f;
#pragma unroll
    for (int j = 0; j < 16; ++j) { e[j] = __expf(x[j] - m); s += e[j]; }
#pragma unroll
    for (int o = 32; o; o >>= 1) s += __shfl_xor(s, o);
    if (lane == 0) redsum[wid] = s;
    __syncthreads();
    s = redsum[0] + redsum[1] + redsum[2] + redsum[3];
    float inv = 1.f / s;

    us8 o0, o1;
#pragma unroll
    for (int j = 0; j < 8; ++j) { o0[j] = f2bf(e[j] * inv); o1[j] = f2bf(e[8 + j] * inv); }
    *(us8*)(rp + t * 16) = o0;
    *(us8*)(rp + t * 16 + 8) = o1;
}

extern "C" void kernel_launch(void* const* d_in, const int* in_sizes, int n_in,
                              void* d_out, int out_size, void* d_ws, size_t ws_size,
                              hipStream_t stream) {
    (void)in_sizes; (void)n_in; (void)out_size; (void)ws_size;
    const float* q  = (const float*)d_in[0];
    const float* k  = (const float*)d_in[1];
    const float* v  = (const float*)d_in[2];
    const float* Wq = (const float*)d_in[3];
    const float* bq = (const float*)d_in[4];
    const float* Wk = (const float*)d_in[5];
    const float* bk = (const float*)d_in[6];
    const float* Wv = (const float*)d_in[7];
    const float* bv = (const float*)d_in[8];
    float* out = (float*)d_out;

    constexpr long MB = 1l << 20;
    char* ws = (char*)d_ws;
    u16* pq  = (u16*)(ws + 0 * MB);     // 32 MB  [16384,1024] bf16
    u16* pk  = (u16*)(ws + 32 * MB);    // 32 MB
    u16* pvT = (u16*)(ws + 64 * MB);    // 32 MB  [1024,16384] bf16 (pv transposed)
    u16* Wqb = (u16*)(ws + 96 * MB);    // 2 MB
    u16* Wkb = (u16*)(ws + 98 * MB);    // 2 MB
    u16* Wvb = (u16*)(ws + 100 * MB);   // 2 MB
    u16* qb  = (u16*)(ws + 104 * MB);   // 32 MB (dead after pq GEMM)
    u16* kb  = (u16*)(ws + 136 * MB);   // 32 MB (dead after pk GEMM)
    u16* vb  = (u16*)(ws + 168 * MB);   // 32 MB -> ws end = 200 MB
    u16* S2  = (u16*)(ws + 104 * MB);   // 64 MB (2 batches), aliases qb+kb (dead)

    const int L = 4096, E = 1024, NB = 4;
    const int n8_x = (NB * L * E) / 8;
    const int n8_w = (E * E) / 8;

    cvt_f32_bf16<<<2048, 256, 0, stream>>>(q, qb, n8_x);
    cvt_f32_bf16<<<2048, 256, 0, stream>>>(k, kb, n8_x);
    cvt_f32_bf16<<<2048, 256, 0, stream>>>(v, vb, n8_x);
    cvt_f32_bf16<<<512, 256, 0, stream>>>(Wq, Wqb, n8_w);
    cvt_f32_bf16<<<512, 256, 0, stream>>>(Wk, Wkb, n8_w);
    cvt_f32_bf16<<<512, 256, 0, stream>>>(Wv, Wvb, n8_w);

    // projections: pq = q@Wq^T + bq   (M=16384 -> gy=64, N=1024 -> gx=8)
    dim3 gproj(8, 64, 1);
    gemm256<0><<<gproj, 512, 0, stream>>>(qb, Wqb, pq, bq, 1.f, E, E, E, E, 0, 0, 0);
    gemm256<0><<<gproj, 512, 0, stream>>>(kb, Wkb, pk, bk, 1.f, E, E, E, E, 0, 0, 0);
    // pvT = Wv @ v^T + bv[row]   (M=1024 -> gy=4, N=16384 -> gx=128)
    dim3 gpv(128, 4, 1);
    gemm256<1><<<gpv, 512, 0, stream>>>(Wvb, vb, pvT, bv, 1.f, E, E, E, NB * L, 0, 0, 0);

    const float scale = 0.03125f;  // 1/sqrt(1024)
    for (int p = 0; p < 2; ++p) {
        const long zb = p * 2;
        // S = pq @ pk^T * scale -> fp16   (M=N=4096 -> gy=16, gx=32; z=2 batches)
        dim3 gs(32, 16, 2);
        gemm256<2><<<gs, 512, 0, stream>>>(pq + zb * L * E, pk + zb * L * E, (void*)S2,
                                           nullptr, scale, E, E, E, L,
                                           (long)L * E, (long)L * E, (long)L * L);
        // softmax over 2*L rows, in place fp16 -> bf16
        softmax_row<<<2 * L, 256, 0, stream>>>(S2, L);
        // out = attn @ pvT^T   (M=4096 -> gy=16, N=1024 -> gx=8; z=2)
        dim3 gp(8, 16, 2);
        gemm256<3><<<gp, 512, 0, stream>>>(S2, pvT + zb * L, out + zb * L * E,
                                           nullptr, 1.f, L, L, NB * L, E,
                                           (long)L * L, (long)L, (long)L * E);
    }
}

// Round 5
// 502.852 us; speedup vs baseline: 1.7163x; 1.0338x over previous
//
#include <hip/hip_runtime.h>

typedef unsigned short u16;
typedef __bf16  bf16x8 __attribute__((ext_vector_type(8)));
typedef float   f32x4  __attribute__((ext_vector_type(4)));
typedef unsigned short us8 __attribute__((ext_vector_type(8)));
typedef _Float16 f16x8 __attribute__((ext_vector_type(8)));
typedef float   fl4   __attribute__((ext_vector_type(4)));

#define AS1 __attribute__((address_space(1)))
#define AS3 __attribute__((address_space(3)))

__device__ __forceinline__ u16 f2bf(float f) {
    union { float f; unsigned u; } x; x.f = f;
    unsigned r = x.u + 0x7fffu + ((x.u >> 16) & 1u);
    return (u16)(r >> 16);
}

// ---------------- fp32 -> bf16 cast, vectorized ----------------
__global__ __launch_bounds__(256) void cvt_f32_bf16(const float* __restrict__ in,
                                                    u16* __restrict__ out, int n8) {
    int i = blockIdx.x * blockDim.x + threadIdx.x;
    int stride = gridDim.x * blockDim.x;
    for (; i < n8; i += stride) {
        const fl4* p = (const fl4*)(in + (long)i * 8);
        fl4 a = p[0], b = p[1];
        us8 o;
#pragma unroll
        for (int j = 0; j < 4; ++j) { o[j] = f2bf(a[j]); o[4 + j] = f2bf(b[j]); }
        *(us8*)(out + (long)i * 8) = o;
    }
}

// ---------------- 128x128 tile bf16 GEMM, C = A * B^T ----------------
// Drain-all schedule (provably race-free), 4 waves (2x2), BK=64,
// LDS 64 KiB -> 2 blocks/CU so two blocks' LDS-read and MFMA phases
// anti-phase and overlap across the CU (m114 co-scheduling).
// Swizzled LDS (conflict-free), XCD-bijective block swizzle, setprio.
// MODE 0: bf16 out + bias[col]; MODE 1: bf16 out + bias[row];
// MODE 2: fp16 out * scale;     MODE 3: fp32 out.
template <int MODE>
__global__ __launch_bounds__(256, 2) void gemm128(const u16* __restrict__ A,
                                                  const u16* __restrict__ B,
                                                  void* __restrict__ Cout,
                                                  const float* __restrict__ bias,
                                                  float scale, int K,
                                                  int lda, int ldb, int ldc,
                                                  long sAz, long sBz, long sCz) {
    // per buffer: A 128x64 bf16 = 16384 B, B 128x64 bf16 = 16384 B -> 32768 B; x2 = 64 KiB
    __shared__ alignas(16) char lds8[2 * 32768];

    const int t    = threadIdx.x;
    const int lane = t & 63;
    const int wid  = t >> 6;      // 0..3
    const int wr   = wid >> 1;    // 0..1  (64-row slice of 128)
    const int wc   = wid & 1;     // 0..1  (64-col slice of 128)
    const int fr   = lane & 15;
    const int kq   = lane >> 4;

    // XCD-bijective block swizzle (nwg % 8 == 0 for all our launches)
    const int gx  = gridDim.x;
    const int nwg = gx * gridDim.y;
    const int wg  = blockIdx.y * gx + blockIdx.x;
    const int swz = (wg & 7) * (nwg >> 3) + (wg >> 3);
    const long brow = (long)(swz / gx) * 128;
    const long bcol = (long)(swz % gx) * 128;

    const u16* Az = A + sAz * blockIdx.z;
    const u16* Bz = B + sBz * blockIdx.z;

    // staging: 4 rounds each for A and B; round r covers rows r*32+trow.
    // physical LDS byte = row*128 + ((chunk)^(row&7))*16, staged linearly as
    // dest = r*4096 + t*16 with pre-swizzled global chunk (t&7)^(trow&7).
    const int trow = t >> 3;                  // 0..31
    const int tc8  = ((t & 7) ^ (trow & 7)) * 8;
    long offA[4], offB[4];
#pragma unroll
    for (int r = 0; r < 4; ++r) offA[r] = (brow + r * 32 + trow) * (long)lda + tc8;
#pragma unroll
    for (int r = 0; r < 4; ++r) offB[r] = (bcol + r * 32 + trow) * (long)ldb + tc8;

    // lane read offsets (swizzled): byte = row*128 + ((ksub*4+kq)^(row&7))*16
    int aRow[4], bRow[4], aCh[2];
#pragma unroll
    for (int m = 0; m < 4; ++m) aRow[m] = (wr * 64 + m * 16 + fr) * 128;
#pragma unroll
    for (int n = 0; n < 4; ++n) bRow[n] = 16384 + (wc * 64 + n * 16 + fr) * 128;
#pragma unroll
    for (int ks = 0; ks < 2; ++ks) aCh[ks] = (((ks << 2) | kq) ^ (fr & 7)) * 16;

    const int NT = K >> 6;
    f32x4 acc[4][4] = {};

    // ---- prologue: stage tile 0 into buffer 0, full drain
    {
        char* bb0 = lds8;
#pragma unroll
        for (int r = 0; r < 4; ++r)
            __builtin_amdgcn_global_load_lds((const AS1 unsigned*)(Az + offA[r]),
                                             (AS3 unsigned*)(bb0 + r * 4096 + t * 16), 16, 0, 0);
#pragma unroll
        for (int r = 0; r < 4; ++r)
            __builtin_amdgcn_global_load_lds((const AS1 unsigned*)(Bz + offB[r]),
                                             (AS3 unsigned*)(bb0 + 16384 + r * 4096 + t * 16), 16, 0, 0);
    }
    __syncthreads();

    int cur = 0;
    for (int T = 0; T < NT; ++T) {
        char* bb  = lds8 + cur * 32768;
        char* bbn = lds8 + (cur ^ 1) * 32768;

        // ---- issue next-tile stage FIRST: latency covered by this tile's work.
        if (T + 1 < NT) {
            const long kcol = (long)(T + 1) << 6;
#pragma unroll
            for (int r = 0; r < 4; ++r)
                __builtin_amdgcn_global_load_lds((const AS1 unsigned*)(Az + offA[r] + kcol),
                                                 (AS3 unsigned*)(bbn + r * 4096 + t * 16), 16, 0, 0);
#pragma unroll
            for (int r = 0; r < 4; ++r)
                __builtin_amdgcn_global_load_lds((const AS1 unsigned*)(Bz + offB[r] + kcol),
                                                 (AS3 unsigned*)(bbn + 16384 + r * 4096 + t * 16), 16, 0, 0);
        }

        // ---- read all fragments for this tile (16 x ds_read_b128, conflict-free)
        bf16x8 af[2][4], bfv[2][4];
#pragma unroll
        for (int ks = 0; ks < 2; ++ks)
#pragma unroll
            for (int m = 0; m < 4; ++m)
                af[ks][m] = *(const bf16x8*)(bb + aRow[m] + aCh[ks]);
#pragma unroll
        for (int ks = 0; ks < 2; ++ks)
#pragma unroll
            for (int n = 0; n < 4; ++n)
                bfv[ks][n] = *(const bf16x8*)(bb + bRow[n] + aCh[ks]);

        asm volatile("s_waitcnt lgkmcnt(0)" ::: "memory");
        __builtin_amdgcn_sched_barrier(0);
        __builtin_amdgcn_s_setprio(1);
#pragma unroll
        for (int ks = 0; ks < 2; ++ks)
#pragma unroll
            for (int m = 0; m < 4; ++m)
#pragma unroll
                for (int n = 0; n < 4; ++n)
                    acc[m][n] = __builtin_amdgcn_mfma_f32_16x16x32_bf16(af[ks][m], bfv[ks][n], acc[m][n], 0, 0, 0);
        __builtin_amdgcn_s_setprio(0);
        __builtin_amdgcn_sched_barrier(0);

        // full drain: stage loads landed, all LDS reads done -> next tile safe
        __syncthreads();
        cur ^= 1;
    }

    // ---- epilogue: C/D layout col=lane&15, row=(lane>>4)*4+j
    const long crow = brow + wr * 64;
    const long ccol = bcol + wc * 64;
    const long cz = sCz * blockIdx.z;
#pragma unroll
    for (int m = 0; m < 4; ++m) {
#pragma unroll
        for (int n = 0; n < 4; ++n) {
#pragma unroll
            for (int j = 0; j < 4; ++j) {
                long r = crow + m * 16 + kq * 4 + j;
                long c = ccol + n * 16 + fr;
                float vv = acc[m][n][j];
                if (MODE == 0)      { vv += bias[c]; ((u16*)Cout)[cz + r * ldc + c] = f2bf(vv); }
                else if (MODE == 1) { vv += bias[r]; ((u16*)Cout)[cz + r * ldc + c] = f2bf(vv); }
                else if (MODE == 2) { ((_Float16*)Cout)[cz + r * ldc + c] = (_Float16)(vv * scale); }
                else                { ((float*)Cout)[cz + r * ldc + c] = vv; }
            }
        }
    }
}

// ---------------- row softmax: fp16 in -> bf16 out, in place, L=4096 ----------------
__global__ __launch_bounds__(256) void softmax_row(u16* __restrict__ S, int L) {
    const long row = blockIdx.x;
    u16* rp = S + row * L;
    const int t = threadIdx.x;
    const int lane = t & 63, wid = t >> 6;

    f16x8 h0 = *(const f16x8*)(rp + t * 16);
    f16x8 h1 = *(const f16x8*)(rp + t * 16 + 8);
    float x[16];
#pragma unroll
    for (int j = 0; j < 8; ++j) { x[j] = (float)h0[j]; x[8 + j] = (float)h1[j]; }

    float m = -1e30f;
#pragma unroll
    for (int j = 0; j < 16; ++j) m = fmaxf(m, x[j]);
#pragma unroll
    for (int o = 32; o; o >>= 1) m = fmaxf(m, __shfl_xor(m, o));

    __shared__ float redmax[4], redsum[4];
    if (lane == 0) redmax[wid] = m;
    __syncthreads();
    m = fmaxf(fmaxf(redmax[0], redmax[1]), fmaxf(redmax[2], redmax[3]));

    float e[16], s = 0.f;
#pragma unroll
    for (int j = 0; j < 16; ++j) { e[j] = __expf(x[j] - m); s += e[j]; }
#pragma unroll
    for (int o = 32; o; o >>= 1) s += __shfl_xor(s, o);
    if (lane == 0) redsum[wid] = s;
    __syncthreads();
    s = redsum[0] + redsum[1] + redsum[2] + redsum[3];
    float inv = 1.f / s;

    us8 o0, o1;
#pragma unroll
    for (int j = 0; j < 8; ++j) { o0[j] = f2bf(e[j] * inv); o1[j] = f2bf(e[8 + j] * inv); }
    *(us8*)(rp + t * 16) = o0;
    *(us8*)(rp + t * 16 + 8) = o1;
}

extern "C" void kernel_launch(void* const* d_in, const int* in_sizes, int n_in,
                              void* d_out, int out_size, void* d_ws, size_t ws_size,
                              hipStream_t stream) {
    (void)in_sizes; (void)n_in; (void)out_size; (void)ws_size;
    const float* q  = (const float*)d_in[0];
    const float* k  = (const float*)d_in[1];
    const float* v  = (const float*)d_in[2];
    const float* Wq = (const float*)d_in[3];
    const float* bq = (const float*)d_in[4];
    const float* Wk = (const float*)d_in[5];
    const float* bk = (const float*)d_in[6];
    const float* Wv = (const float*)d_in[7];
    const float* bv = (const float*)d_in[8];
    float* out = (float*)d_out;

    constexpr long MB = 1l << 20;
    char* ws = (char*)d_ws;
    u16* pq  = (u16*)(ws + 0 * MB);     // 32 MB  [16384,1024] bf16
    u16* pk  = (u16*)(ws + 32 * MB);    // 32 MB
    u16* pvT = (u16*)(ws + 64 * MB);    // 32 MB  [1024,16384] bf16 (pv transposed)
    u16* Wqb = (u16*)(ws + 96 * MB);    // 2 MB
    u16* Wkb = (u16*)(ws + 98 * MB);    // 2 MB
    u16* Wvb = (u16*)(ws + 100 * MB);   // 2 MB
    u16* qb  = (u16*)(ws + 104 * MB);   // 32 MB (dead after pq GEMM)
    u16* kb  = (u16*)(ws + 136 * MB);   // 32 MB (dead after pk GEMM)
    u16* vb  = (u16*)(ws + 168 * MB);   // 32 MB -> ws end = 200 MB
    u16* S2  = (u16*)(ws + 104 * MB);   // 64 MB (2 batches), aliases qb+kb (dead)

    const int L = 4096, E = 1024, NB = 4;
    const int n8_x = (NB * L * E) / 8;
    const int n8_w = (E * E) / 8;

    cvt_f32_bf16<<<2048, 256, 0, stream>>>(q, qb, n8_x);
    cvt_f32_bf16<<<2048, 256, 0, stream>>>(k, kb, n8_x);
    cvt_f32_bf16<<<2048, 256, 0, stream>>>(v, vb, n8_x);
    cvt_f32_bf16<<<512, 256, 0, stream>>>(Wq, Wqb, n8_w);
    cvt_f32_bf16<<<512, 256, 0, stream>>>(Wk, Wkb, n8_w);
    cvt_f32_bf16<<<512, 256, 0, stream>>>(Wv, Wvb, n8_w);

    // projections: pq = q@Wq^T + bq   (M=16384 -> gy=128, N=1024 -> gx=8)
    dim3 gproj(8, 128, 1);
    gemm128<0><<<gproj, 256, 0, stream>>>(qb, Wqb, pq, bq, 1.f, E, E, E, E, 0, 0, 0);
    gemm128<0><<<gproj, 256, 0, stream>>>(kb, Wkb, pk, bk, 1.f, E, E, E, E, 0, 0, 0);
    // pvT = Wv @ v^T + bv[row]   (M=1024 -> gy=8, N=16384 -> gx=128)
    dim3 gpv(128, 8, 1);
    gemm128<1><<<gpv, 256, 0, stream>>>(Wvb, vb, pvT, bv, 1.f, E, E, E, NB * L, 0, 0, 0);

    const float scale = 0.03125f;  // 1/sqrt(1024)
    for (int p = 0; p < 2; ++p) {
        const long zb = p * 2;
        // S = pq @ pk^T * scale -> fp16   (M=N=4096 -> gy=32, gx=32; z=2 batches)
        dim3 gs(32, 32, 2);
        gemm128<2><<<gs, 256, 0, stream>>>(pq + zb * L * E, pk + zb * L * E, (void*)S2,
                                           nullptr, scale, E, E, E, L,
                                           (long)L * E, (long)L * E, (long)L * L);
        // softmax over 2*L rows, in place fp16 -> bf16
        softmax_row<<<2 * L, 256, 0, stream>>>(S2, L);
        // out = attn @ pvT^T   (M=4096 -> gy=32, N=1024 -> gx=8; z=2)
        dim3 gp(8, 32, 2);
        gemm128<3><<<gp, 256, 0, stream>>>(S2, pvT + zb * L, out + zb * L * E,
                                           nullptr, 1.f, L, L, NB * L, E,
                                           (long)L * L, (long)L, (long)L * E);
    }
}